// Round 15
// baseline (440.799 us; speedup 1.0000x reference)
//
#include <hip/hip_runtime.h>
#include <math.h>

#define S_LEN 2048
#define DMODEL 2560
#define NH 32
#define NKV 8
#define HD 128
#define QDIM (NH*HD)     // 4096
#define KVDIM (NKV*HD)   // 1024
#define NB (QDIM + 2*KVDIM)   // 6144 packed B rows
#define ROPE_THETA 5000000.0
#define QK_SCALE 0.08838834764831843f

typedef __attribute__((ext_vector_type(8))) short s16x8;
typedef __attribute__((ext_vector_type(4))) float f32x4;
typedef __attribute__((ext_vector_type(16))) float f32x16;
typedef unsigned short u16;

#define MFMA16(a,b,c) __builtin_amdgcn_mfma_f32_16x16x32_bf16((a),(b),(c),0,0,0)
#define MFMA32(a,b,c) __builtin_amdgcn_mfma_f32_32x32x16_bf16((a),(b),(c),0,0,0)

__device__ __forceinline__ u16 f2bf(float x) {
    union { float f; unsigned u; } v; v.f = x;
    unsigned r = v.u + 0x7FFFu + ((v.u >> 16) & 1u);
    return (u16)(r >> 16);
}
__device__ __forceinline__ float bf2f(u16 h) {
    union { unsigned u; float f; } v; v.u = ((unsigned)h) << 16;
    return v.f;
}
__device__ __forceinline__ unsigned pk2(float a, float b) {
    return (unsigned)f2bf(a) | ((unsigned)f2bf(b) << 16);
}

// K arrays: [rows][16 units of 8 bf16], XOR all 4 unit bits.
__device__ __forceinline__ int lswK(int row, int kb) {
    return ((row * 16 + (kb ^ (row & 15))) << 3);
}

// async global->LDS, 16B per lane; LDS dest = wave-uniform base + lane*16.
__device__ __forceinline__ void gload16(const void* g, void* l) {
    __builtin_amdgcn_global_load_lds(
        (const __attribute__((address_space(1))) void*)g,
        (__attribute__((address_space(3))) void*)l, 16, 0, 0);
}

// ---------------------------------------------------------------------------
// prep_all: all input-side elementwise work in ONE launch.
// ---------------------------------------------------------------------------
#define N4_X   (S_LEN*DMODEL/4)
#define N4_WQ  (QDIM*DMODEL/4)
#define N4_WKV (KVDIM*DMODEL/4)
#define N4_WO  (DMODEL*QDIM/4)
#define N_TAB  (S_LEN*64)
#define PREP_TOTAL (N4_X + N4_WQ + N4_WKV + N4_WKV + N4_WO + N_TAB)

__device__ __forceinline__ void split4(const float* in, long i,
                                       u16* hi, u16* lo) {
    float4 v = ((const float4*)in)[i];
    float a[4] = {v.x, v.y, v.z, v.w};
    u16 hh[4], ll[4];
    #pragma unroll
    for (int j = 0; j < 4; ++j) {
        hh[j] = f2bf(a[j]);
        ll[j] = f2bf(a[j] - bf2f(hh[j]));
    }
    ((uint2*)hi)[i] = make_uint2((unsigned)hh[0] | ((unsigned)hh[1] << 16),
                                 (unsigned)hh[2] | ((unsigned)hh[3] << 16));
    ((uint2*)lo)[i] = make_uint2((unsigned)ll[0] | ((unsigned)ll[1] << 16),
                                 (unsigned)ll[2] | ((unsigned)ll[3] << 16));
}
__device__ __forceinline__ void cvt4(const float* in, long i, u16* out) {
    float4 v = ((const float4*)in)[i];
    u16 h0 = f2bf(v.x), h1 = f2bf(v.y), h2 = f2bf(v.z), h3 = f2bf(v.w);
    ((uint2*)out)[i] = make_uint2((unsigned)h0 | ((unsigned)h1 << 16),
                                  (unsigned)h2 | ((unsigned)h3 << 16));
}

__global__ __launch_bounds__(256)
void prep_all(const float* __restrict__ x, const float* __restrict__ w_q,
              const float* __restrict__ w_k, const float* __restrict__ w_v,
              const float* __restrict__ w_o, const int* __restrict__ pos,
              u16* __restrict__ XH, u16* __restrict__ XL,
              u16* __restrict__ WBH, u16* __restrict__ WBL,
              u16* __restrict__ WOH,
              float* __restrict__ cost, float* __restrict__ sint) {
    long i = (long)blockIdx.x * 256 + threadIdx.x;
    if (i < N4_X) { split4(x, i, XH, XL); return; }
    i -= N4_X;
    if (i < N4_WQ) { split4(w_q, i, WBH, WBL); return; }
    i -= N4_WQ;
    if (i < N4_WKV) {
        split4(w_k, i, WBH + (size_t)QDIM * DMODEL, WBL + (size_t)QDIM * DMODEL);
        return;
    }
    i -= N4_WKV;
    if (i < N4_WKV) {
        split4(w_v, i, WBH + (size_t)(QDIM + KVDIM) * DMODEL,
                       WBL + (size_t)(QDIM + KVDIM) * DMODEL);
        return;
    }
    i -= N4_WKV;
    if (i < N4_WO) { cvt4(w_o, i, WOH); return; }
    i -= N4_WO;
    if (i < N_TAB) {
        int s = (int)(i >> 6), j = (int)(i & 63);
        double inv = pow((double)ROPE_THETA, -(double)j / 64.0);
        double ang = (double)pos[s] * inv;
        cost[i] = (float)cos(ang);
        sint[i] = (float)sin(ang);
    }
}

// ---------------------------------------------------------------------------
// merged rope: q (scaled, ws) + k (in-place fp32 cache) -> bf16 hi/lo splits
// ---------------------------------------------------------------------------
__global__ __launch_bounds__(256)
void rope_qk_split(float* __restrict__ q32, float* __restrict__ k,
                   const float* __restrict__ cost, const float* __restrict__ sint,
                   u16* __restrict__ qhh, u16* __restrict__ qll,
                   u16* __restrict__ khh, u16* __restrict__ kll) {
    int idx = blockIdx.x * 256 + threadIdx.x;
    if (idx < S_LEN * NH * 64) {
        int j = idx & 63;
        int h = (idx >> 6) & 31;
        int s = idx >> 11;
        float c = cost[(s << 6) + j], sn = sint[(s << 6) + j];
        size_t base = (size_t)s * QDIM + (size_t)h * HD;
        float x1 = q32[base + j], x2 = q32[base + 64 + j];
        float y1 = (x1 * c - x2 * sn) * QK_SCALE;
        float y2 = (x2 * c + x1 * sn) * QK_SCALE;
        u16 h1 = f2bf(y1), h2 = f2bf(y2);
        qhh[base + j] = h1;      qll[base + j] = f2bf(y1 - bf2f(h1));
        qhh[base + 64 + j] = h2; qll[base + 64 + j] = f2bf(y2 - bf2f(h2));
    } else {
        idx -= S_LEN * NH * 64;
        int j = idx & 63;
        int s = (idx >> 6) & 2047;
        int h = idx >> 17;
        float c = cost[(s << 6) + j], sn = sint[(s << 6) + j];
        size_t base = ((size_t)h * S_LEN + s) * HD;
        float x1 = k[base + j], x2 = k[base + 64 + j];
        float y1 = x1 * c - x2 * sn;
        float y2 = x2 * c + x1 * sn;
        k[base + j] = y1; k[base + 64 + j] = y2;
        u16 h1 = f2bf(y1), h2 = f2bf(y2);
        khh[base + j] = h1;      kll[base + j] = f2bf(y1 - bf2f(h1));
        khh[base + 64 + j] = h2; kll[base + 64 + j] = f2bf(y2 - bf2f(h2));
    }
}

// ---------------------------------------------------------------------------
// V^T builder: v [8][2048][128] fp32 -> vt [8][128][2048] bf16 (coalesced).
// ---------------------------------------------------------------------------
__global__ __launch_bounds__(256)
void vt_transpose(const float* __restrict__ v, u16* __restrict__ vt) {
    __shared__ u16 t[64][80];
    const int kvh = blockIdx.y;
    const int st = blockIdx.x >> 1, dt = blockIdx.x & 1;
    const int tid = threadIdx.x;
    const int r = tid & 15, c4 = (tid >> 4) * 4;
    const float* vb = v + ((size_t)kvh * S_LEN + st * 64) * HD + dt * 64;
    #pragma unroll
    for (int p = 0; p < 4; ++p) {
        int row = p * 16 + r;
        float4 x = *(const float4*)&vb[(size_t)row * HD + c4];
        t[c4 + 0][row] = f2bf(x.x);
        t[c4 + 1][row] = f2bf(x.y);
        t[c4 + 2][row] = f2bf(x.z);
        t[c4 + 3][row] = f2bf(x.w);
    }
    __syncthreads();
    #pragma unroll
    for (int p = 0; p < 2; ++p) {
        int idx = p * 256 + tid;
        int dr = idx >> 3, sc = idx & 7;
        size_t o = ((size_t)kvh * HD + dt * 64 + dr) * S_LEN + st * 64 + sc * 8;
        *(int4*)&vt[o] = *(const int4*)&t[dr][sc * 8];
    }
}

// ---------------------------------------------------------------------------
// gemm_qkv5: 8-phase deep-pipelined fused QKV projection (m201 template port).
// C[2048][6144] = 3-segment split-3 GEMM (A=[XH,XH,XL], B=[WBH,WBL,WBH]).
// BM=256, BN=192, BK=64; 512 thr = 8 waves (2M x 4N), per-wave 128x48.
// Per K-tile: 4 phases {ds-read subtile | 1-2 prefetch gloads | barrier |
// lgkmcnt(0) | setprio(1) 12xMFMA setprio(0) | barrier}. 2-buffer LDS
// (112KB), prefetch tile T+1 during tile T, vmcnt(0)+barrier gate per tile.
// Grid 256 exactly; m-tile = bid&7 (XCD-pinned A panel).
// K-traversal order identical to qkv3 -> bit-identical numerics.
// ---------------------------------------------------------------------------
__global__ __launch_bounds__(512, 2)
void gemm_qkv5(const u16* __restrict__ XH, const u16* __restrict__ XL,
               const u16* __restrict__ WBH, const u16* __restrict__ WBL,
               float* __restrict__ Q32, float* __restrict__ out_k,
               float* __restrict__ out_v) {
    __shared__ u16 SM[57344];   // A: 2 x 16384 u16 (32KB) | B: 2 x 12288 u16 (24KB)
    const int bid = blockIdx.x;
    const int m0 = (bid & 7) * 256;
    const int n0 = (bid >> 3) * 192;
    const int tid = threadIdx.x, lane = tid & 63, w = tid >> 6;
    const int q4 = lane >> 4, r15 = lane & 15;
    const int wm = (w >> 2) * 128, wn = (w & 3) * 48;

    f32x4 acc[8][3];
    #pragma unroll
    for (int i = 0; i < 8; ++i)
        #pragma unroll
        for (int jj = 0; jj < 3; ++jj) acc[i][jj] = (f32x4)(0.0f);

    // one gload call = 512 threads x 16B = 8KB = 512 units of 8 u16.
    auto stageAcall = [&](int T, int c) {
        int b = T & 1;
        int seg = T / 40, koff = (T - seg * 40) * 64;
        const u16* Ag = (seg == 2) ? XL : XH;
        int base = c * 512 + w * 64;
        int idx = base + lane;
        int row = idx >> 3, s3 = idx & 7;
        int un = s3 ^ (row & 7);
        gload16(Ag + (size_t)(m0 + row) * DMODEL + koff + un * 8,
                &SM[b * 16384 + base * 8]);
    };
    auto stageBcall = [&](int T, int c) {
        int b = T & 1;
        int seg = T / 40, koff = (T - seg * 40) * 64;
        const u16* Bg = (seg == 1) ? WBL : WBH;
        int base = c * 512 + w * 64;
        int idx = base + lane;
        int row = idx >> 3, s3 = idx & 7;
        int un = s3 ^ (row & 7);
        gload16(Bg + (size_t)(n0 + row) * DMODEL + koff + un * 8,
                &SM[32768 + b * 12288 + base * 8]);
    };

    // fragment reads from [row][8 units] tiles, unit XOR-swizzled by row&7
    auto Ard = [&](const u16* As, int row, int kk) {
        int un = kk * 4 + q4;
        return *(const s16x8*)&As[(row * 8 + (un ^ (row & 7))) * 8];
    };
    auto Brd = [&](const u16* Bs, int row, int kk) {
        int un = kk * 4 + q4;
        return *(const s16x8*)&Bs[(row * 8 + (un ^ (row & 7))) * 8];
    };

    // prologue: tile 0 fully staged (7 calls)
    stageAcall(0, 0); stageAcall(0, 1); stageAcall(0, 2); stageAcall(0, 3);
    stageBcall(0, 0); stageBcall(0, 1); stageBcall(0, 2);

    const int NT = 3 * DMODEL / 64;   // 120 K-tiles
    for (int T = 0; T < NT; ++T) {
        const int b = T & 1;
        u16* As = &SM[b * 16384];
        u16* Bs = &SM[32768 + b * 12288];
        const bool pf = (T + 1 < NT);

        // gate: tile T resident (its 7 calls were the only outstanding loads)
        __builtin_amdgcn_sched_barrier(0);
        asm volatile("s_waitcnt vmcnt(0)" ::: "memory");
        __builtin_amdgcn_s_barrier();
        __builtin_amdgcn_sched_barrier(0);

        #pragma unroll
        for (int kk = 0; kk < 2; ++kk) {
            // ---- phase (kk, mhalf=0) ----
            s16x8 bf0 = Brd(Bs, wn + r15, kk);
            s16x8 bf1 = Brd(Bs, wn + 16 + r15, kk);
            s16x8 bf2 = Brd(Bs, wn + 32 + r15, kk);
            s16x8 a0 = Ard(As, wm + r15, kk);
            s16x8 a1 = Ard(As, wm + 16 + r15, kk);
            s16x8 a2 = Ard(As, wm + 32 + r15, kk);
            s16x8 a3 = Ard(As, wm + 48 + r15, kk);
            if (pf) {
                if (kk == 0) { stageAcall(T + 1, 0); stageAcall(T + 1, 1); }
                else         { stageBcall(T + 1, 0); stageBcall(T + 1, 1); }
            }
            __builtin_amdgcn_s_barrier();
            asm volatile("s_waitcnt lgkmcnt(0)" ::: "memory");
            __builtin_amdgcn_sched_barrier(0);
            __builtin_amdgcn_s_setprio(1);
            acc[0][0] = MFMA16(a0, bf0, acc[0][0]);
            acc[0][1] = MFMA16(a0, bf1, acc[0][1]);
            acc[0][2] = MFMA16(a0, bf2, acc[0][2]);
            acc[1][0] = MFMA16(a1, bf0, acc[1][0]);
            acc[1][1] = MFMA16(a1, bf1, acc[1][1]);
            acc[1][2] = MFMA16(a1, bf2, acc[1][2]);
            acc[2][0] = MFMA16(a2, bf0, acc[2][0]);
            acc[2][1] = MFMA16(a2, bf1, acc[2][1]);
            acc[2][2] = MFMA16(a2, bf2, acc[2][2]);
            acc[3][0] = MFMA16(a3, bf0, acc[3][0]);
            acc[3][1] = MFMA16(a3, bf1, acc[3][1]);
            acc[3][2] = MFMA16(a3, bf2, acc[3][2]);
            __builtin_amdgcn_s_setprio(0);
            __builtin_amdgcn_s_barrier();

            // ---- phase (kk, mhalf=1) ----
            s16x8 a4 = Ard(As, wm + 64 + r15, kk);
            s16x8 a5 = Ard(As, wm + 80 + r15, kk);
            s16x8 a6 = Ard(As, wm + 96 + r15, kk);
            s16x8 a7 = Ard(As, wm + 112 + r15, kk);
            if (pf) {
                if (kk == 0) { stageAcall(T + 1, 2); stageAcall(T + 1, 3); }
                else         { stageBcall(T + 1, 2); }
            }
            __builtin_amdgcn_s_barrier();
            asm volatile("s_waitcnt lgkmcnt(0)" ::: "memory");
            __builtin_amdgcn_sched_barrier(0);
            __builtin_amdgcn_s_setprio(1);
            acc[4][0] = MFMA16(a4, bf0, acc[4][0]);
            acc[4][1] = MFMA16(a4, bf1, acc[4][1]);
            acc[4][2] = MFMA16(a4, bf2, acc[4][2]);
            acc[5][0] = MFMA16(a5, bf0, acc[5][0]);
            acc[5][1] = MFMA16(a5, bf1, acc[5][1]);
            acc[5][2] = MFMA16(a5, bf2, acc[5][2]);
            acc[6][0] = MFMA16(a6, bf0, acc[6][0]);
            acc[6][1] = MFMA16(a6, bf1, acc[6][1]);
            acc[6][2] = MFMA16(a6, bf2, acc[6][2]);
            acc[7][0] = MFMA16(a7, bf0, acc[7][0]);
            acc[7][1] = MFMA16(a7, bf1, acc[7][1]);
            acc[7][2] = MFMA16(a7, bf2, acc[7][2]);
            __builtin_amdgcn_s_setprio(0);
            __builtin_amdgcn_s_barrier();
        }
    }

    // epilogue: D layout col = lane&15, row = (lane>>4)*4 + r; region branch
    #pragma unroll
    for (int i = 0; i < 8; ++i) {
        #pragma unroll
        for (int jj = 0; jj < 3; ++jj) {
            int col = n0 + wn + jj * 16 + r15;
            #pragma unroll
            for (int r = 0; r < 4; ++r) {
                int row = m0 + wm + i * 16 + q4 * 4 + r;
                float v = acc[i][jj][r];
                if (col < QDIM) {
                    Q32[(size_t)row * QDIM + col] = v;
                } else if (col < QDIM + KVDIM) {
                    int cc = col - QDIM;
                    out_k[((size_t)(cc >> 7) * S_LEN + row) * HD + (cc & 127)] = v;
                } else {
                    int cc = col - QDIM - KVDIM;
                    out_v[((size_t)(cc >> 7) * S_LEN + row) * HD + (cc & 127)] = v;
                }
            }
        }
    }
}

// ---------------------------------------------------------------------------
// gemm_o3: deep-pipelined O projection (round-11/14 structure).
// ---------------------------------------------------------------------------
__global__ __launch_bounds__(256, 2)
void gemm_o3(const u16* __restrict__ AOH, const u16* __restrict__ WOH,
             float* __restrict__ out) {
    __shared__ u16 SM[36864];     // A: 4 x 4096 | B: 4 x 5120 (u16)
    const int bid = blockIdx.x;
    const int m0 = (bid & 15) * 128;
    const int n0 = (bid >> 4) * 160;
    const int tid = threadIdx.x, lane = tid & 63, w = tid >> 6;
    const int q4 = lane >> 4, r15 = lane & 15;
    const int wm = (w >> 1) * 64, wn = (w & 1) * 80;

    f32x4 acc[4][5];
    #pragma unroll
    for (int i = 0; i < 4; ++i)
        #pragma unroll
        for (int jj = 0; jj < 5; ++jj) acc[i][jj] = (f32x4)(0.0f);

    auto stageA = [&](int j) {
        const int s = j & 3;
        const int koff = j * 32;
        #pragma unroll
        for (int p = 0; p < 2; ++p) {
            int c = p * 4 + w;
            int u = c * 64 + lane;
            int rl = u >> 3;
            int ulog = (u & 7) ^ (rl & 7);
            int grow = m0 + rl * 2 + (ulog >> 2);
            gload16(AOH + (size_t)grow * QDIM + koff + (ulog & 3) * 8,
                    &SM[s * 4096 + c * 512]);
        }
    };
    auto stageB = [&](int j) {
        const int s = j & 3;
        const int koff = j * 32;
        #pragma unroll
        for (int p = 0; p < 3; ++p) {
            int c = p * 4 + w;
            if (c < 10) {
                int u = c * 64 + lane;
                int rl = u >> 3;
                int ulog = (u & 7) ^ (rl & 7);
                int grow = n0 + rl * 2 + (ulog >> 2);
                gload16(WOH + (size_t)grow * QDIM + koff + (ulog & 3) * 8,
                        &SM[16384 + s * 5120 + c * 512]);
            }
        }
    };

    stageA(0); stageB(0); stageA(1); stageB(1);

    const int NT = QDIM / 32;     // 128
    for (int j = 0; j < NT; ++j) {
        const int s = j & 3;
        __builtin_amdgcn_sched_barrier(0);
        if (j + 1 < NT) {
            if (w < 2) { asm volatile("s_waitcnt vmcnt(5)" ::: "memory"); }
            else       { asm volatile("s_waitcnt vmcnt(4)" ::: "memory"); }
        } else {
            asm volatile("s_waitcnt vmcnt(0)" ::: "memory");
        }
        __builtin_amdgcn_s_barrier();
        __builtin_amdgcn_sched_barrier(0);

        if (j + 2 < NT) stageA(j + 2);

        u16* As = &SM[s * 4096];
        u16* Bs = &SM[16384 + s * 5120];
        auto Ard = [&](int i) {
            int row = wm + i * 16 + r15;
            int rl = row >> 1, ulog = (row & 1) * 4 + q4;
            return *(const s16x8*)&As[(rl * 8 + (ulog ^ (rl & 7))) * 8];
        };
        auto Brd = [&](int jj) {
            int row = wn + jj * 16 + r15;
            int rl = row >> 1, ulog = (row & 1) * 4 + q4;
            return *(const s16x8*)&Bs[(rl * 8 + (ulog ^ (rl & 7))) * 8];
        };

        s16x8 bf0 = Brd(0), bf1 = Brd(1), bf2 = Brd(2), bf3 = Brd(3), bf4 = Brd(4);
        s16x8 a0 = Ard(0);
        s16x8 a1 = Ard(1);
        __builtin_amdgcn_s_setprio(1);
        acc[0][0] = MFMA16(a0, bf0, acc[0][0]);
        acc[0][1] = MFMA16(a0, bf1, acc[0][1]);
        acc[0][2] = MFMA16(a0, bf2, acc[0][2]);
        acc[0][3] = MFMA16(a0, bf3, acc[0][3]);
        acc[0][4] = MFMA16(a0, bf4, acc[0][4]);
        __builtin_amdgcn_s_setprio(0);
        if (j + 2 < NT) stageB(j + 2);
        __builtin_amdgcn_s_setprio(1);
        s16x8 a2 = Ard(2);
        acc[1][0] = MFMA16(a1, bf0, acc[1][0]);
        acc[1][1] = MFMA16(a1, bf1, acc[1][1]);
        acc[1][2] = MFMA16(a1, bf2, acc[1][2]);
        acc[1][3] = MFMA16(a1, bf3, acc[1][3]);
        acc[1][4] = MFMA16(a1, bf4, acc[1][4]);
        s16x8 a3 = Ard(3);
        acc[2][0] = MFMA16(a2, bf0, acc[2][0]);
        acc[2][1] = MFMA16(a2, bf1, acc[2][1]);
        acc[2][2] = MFMA16(a2, bf2, acc[2][2]);
        acc[2][3] = MFMA16(a2, bf3, acc[2][3]);
        acc[2][4] = MFMA16(a2, bf4, acc[2][4]);
        acc[3][0] = MFMA16(a3, bf0, acc[3][0]);
        acc[3][1] = MFMA16(a3, bf1, acc[3][1]);
        acc[3][2] = MFMA16(a3, bf2, acc[3][2]);
        acc[3][3] = MFMA16(a3, bf3, acc[3][3]);
        acc[3][4] = MFMA16(a3, bf4, acc[3][4]);
        __builtin_amdgcn_s_setprio(0);
    }

    #pragma unroll
    for (int i = 0; i < 4; ++i) {
        #pragma unroll
        for (int jj = 0; jj < 5; ++jj) {
            int col = n0 + wn + jj * 16 + r15;
            #pragma unroll
            for (int r = 0; r < 4; ++r) {
                int row = m0 + wm + i * 16 + q4 * 4 + r;
                out[(size_t)row * DMODEL + col] = acc[i][jj][r];
            }
        }
    }
}

// ---------------------------------------------------------------------------
// MFMA flash attention v9 (round-11, unchanged): swapped 32x32 QK^T,
// per-lane softmax, KVBLK=32, 3-slot ring, counted-vmcnt gates.
// ---------------------------------------------------------------------------
__global__ __launch_bounds__(256, 2)
void attn_mfma9(const u16* __restrict__ qh, const u16* __restrict__ ql,
                const u16* __restrict__ kh, const u16* __restrict__ kl,
                const u16* __restrict__ vt, u16* __restrict__ aoh) {
    const int bid = blockIdx.x;
    const int kvh = bid & 7;
    const int s6 = bid >> 3;
    const int qst = (s6 < 32) ? s6 : 95 - s6;
    const int KT = qst + 1;

    const int tid = threadIdx.x, lane = tid & 63, w = tid >> 6;
    const int head = kvh * 4 + w;
    const int col = lane & 31;
    const int hi = lane >> 5;

    __shared__ u16 SMEM[36864];

    s16x8 qfh[8], qfl[8];
    {
        size_t qrow = (size_t)qst * 32 + col;
        const u16* qb  = qh + qrow * QDIM + (size_t)head * HD + hi * 8;
        const u16* qb2 = ql + qrow * QDIM + (size_t)head * HD + hi * 8;
        #pragma unroll
        for (int db = 0; db < 8; ++db) {
            qfh[db] = *(const s16x8*)(qb + db * 16);
            qfl[db] = *(const s16x8*)(qb2 + db * 16);
        }
    }

    f32x16 acco[4];
    #pragma unroll
    for (int dt = 0; dt < 4; ++dt) acco[dt] = (f32x16)(0.0f);
    float m = -1e30f, l = 0.f;

    const u16* kbase = kh + (size_t)kvh * S_LEN * HD;
    const u16* lbase = kl + (size_t)kvh * S_LEN * HD;
    const u16* vbase = vt + (size_t)kvh * HD * S_LEN;

    auto stage = [&](int kt, int slot) {
        u16* S = SMEM + slot * 12288;
        #pragma unroll
        for (int i = 0; i < 6; ++i) {
            int c = w + 4 * i;
            if (c < 16) {
                int cc = c & 7;
                int u = cc * 64 + lane;
                int krow = u >> 4;
                int kb = (u & 15) ^ (krow & 15);
                size_t g = (size_t)(kt * 32 + krow) * HD + kb * 8;
                if (c < 8) gload16(kbase + g, S + cc * 512);
                else       gload16(lbase + g, S + 4096 + cc * 512);
            } else {
                int cc = c - 16;
                int u = cc * 64 + lane;
                int R = u >> 3, s3 = u & 7;
                int g3 = s3 ^ (R & 7);
                int d = R * 2 + (g3 >> 2);
                int kb = g3 & 3;
                gload16(vbase + (size_t)d * S_LEN + kt * 32 + kb * 8,
                        S + 8192 + cc * 512);
            }
        }
    };

    stage(0, 0);
    if (KT > 1) stage(1, 1);

    for (int kt = 0; kt < KT; ++kt) {
        const int slot = kt % 3;
        __builtin_amdgcn_sched_barrier(0);
        if (kt + 1 < KT) { asm volatile("s_waitcnt vmcnt(6)" ::: "memory"); }
        else             { asm volatile("s_waitcnt vmcnt(0)" ::: "memory"); }
        __builtin_amdgcn_s_barrier();
        __builtin_amdgcn_sched_barrier(0);
        if (kt + 2 < KT) stage(kt + 2, (kt + 2) % 3);

        u16* Khs = SMEM + slot * 12288;
        u16* Kls = Khs + 4096;
        u16* Vts = Khs + 8192;

        f32x16 sfA = (f32x16)(0.0f), sfB = (f32x16)(0.0f);
        __builtin_amdgcn_s_setprio(1);
        #pragma unroll
        for (int d = 0; d < 4; ++d) {
            int u = d * 2 + hi;
            s16x8 a0h = *(const s16x8*)&Khs[lswK(col, u)];
            s16x8 a0l = *(const s16x8*)&Kls[lswK(col, u)];
            sfA = MFMA32(a0h, qfh[d], sfA);
            sfA = MFMA32(a0l, qfh[d], sfA);
            sfA = MFMA32(a0h, qfl[d], sfA);
        }
        #pragma unroll
        for (int d = 4; d < 8; ++d) {
            int u = d * 2 + hi;
            s16x8 a0h = *(const s16x8*)&Khs[lswK(col, u)];
            s16x8 a0l = *(const s16x8*)&Kls[lswK(col, u)];
            sfB = MFMA32(a0h, qfh[d], sfB);
            sfB = MFMA32(a0l, qfh[d], sfB);
            sfB = MFMA32(a0h, qfl[d], sfB);
        }
        __builtin_amdgcn_s_setprio(0);
        f32x16 sf0 = sfA + sfB;

        if (kt == qst) {
            #pragma unroll
            for (int r = 0; r < 16; ++r) {
                int row = (r & 3) + 8 * (r >> 2) + 4 * hi;
                if (row > col) sf0[r] = -1e30f;
            }
        }

        float pm = sf0[0];
        #pragma unroll
        for (int r = 1; r < 16; ++r) pm = fmaxf(pm, sf0[r]);
        pm = fmaxf(pm, __shfl_xor(pm, 32));

        if (!__all(pm - m <= 8.0f)) {
            float mn = fmaxf(m, pm);
            float corr = __expf(m - mn);
            m = mn; l *= corr;
            float cv[16];
            #pragma unroll
            for (int r = 0; r < 16; ++r)
                cv[r] = __shfl(corr, (r & 3) + 8 * (r >> 2) + 4 * hi);
            #pragma unroll
            for (int dt = 0; dt < 4; ++dt)
                #pragma unroll
                for (int r = 0; r < 16; ++r) acco[dt][r] *= cv[r];
        }

        float p0[16], sum = 0.f;
        #pragma unroll
        for (int r = 0; r < 16; ++r) { p0[r] = __expf(sf0[r] - m); sum += p0[r]; }
        sum += __shfl_xor(sum, 32);
        l += sum;

        unsigned w0[8], x0[8];
        #pragma unroll
        for (int i = 0; i < 8; ++i) w0[i] = pk2(p0[2 * i], p0[2 * i + 1]);
        #pragma unroll
        for (int i = 0; i < 8; ++i) x0[i] = __shfl_xor(w0[i], 32);
        union { unsigned u[4]; s16x8 v; } fa;
        s16x8 pa00, pa01;
        fa.u[0] = hi ? x0[2] : w0[0]; fa.u[1] = hi ? x0[3] : w0[1];
        fa.u[2] = hi ? w0[2] : x0[0]; fa.u[3] = hi ? w0[3] : x0[1];
        pa00 = fa.v;
        fa.u[0] = hi ? x0[6] : w0[4]; fa.u[1] = hi ? x0[7] : w0[5];
        fa.u[2] = hi ? w0[6] : x0[4]; fa.u[3] = hi ? w0[7] : x0[5];
        pa01 = fa.v;

        __builtin_amdgcn_s_setprio(1);
        #pragma unroll
        for (int dt = 0; dt < 4; ++dt) {
            int d = dt * 32 + col;
            int R = d >> 1, r7 = R & 7, par = (d & 1) * 4;
            s16x8 vb00 = *(const s16x8*)&Vts[((R << 3) + ((par | hi) ^ r7)) << 3];
            s16x8 vb01 = *(const s16x8*)&Vts[((R << 3) + ((par | (2 + hi)) ^ r7)) << 3];
            acco[dt] = MFMA32(pa00, vb00, acco[dt]);
            acco[dt] = MFMA32(pa01, vb01, acco[dt]);
        }
        __builtin_amdgcn_s_setprio(0);
    }

    __syncthreads();
    float linv = 1.0f / l;
    float lv[16];
    #pragma unroll
    for (int r = 0; r < 16; ++r)
        lv[r] = __shfl(linv, (r & 3) + 8 * (r >> 2) + 4 * hi);

    u16* ob = SMEM;
    #pragma unroll
    for (int dt = 0; dt < 4; ++dt)
        #pragma unroll
        for (int r = 0; r < 16; ++r) {
            int row = (r & 3) + 8 * (r >> 2) + 4 * hi;
            ob[(w * 32 + row) * 128 + dt * 32 + col] = f2bf(acco[dt][r] * lv[r]);
        }
    __syncthreads();
    #pragma unroll
    for (int p = 0; p < 8; ++p) {
        int i = p * 256 + tid;
        int hq = i >> 4, c8 = (i & 15) * 8;
        int hh = hq >> 5, qq = hq & 31;
        size_t grow = (size_t)qst * 32 + qq;
        *(int4*)&aoh[grow * QDIM + (size_t)(kvh * 4 + hh) * HD + c8] =
            *(const int4*)&ob[hq * 128 + c8];
    }
}

// ---------------------------------------------------------------------------
extern "C" void kernel_launch(void* const* d_in, const int* in_sizes, int n_in,
                              void* d_out, int out_size, void* d_ws, size_t ws_size,
                              hipStream_t stream) {
    const float* x   = (const float*)d_in[0];
    const int*   pos = (const int*)d_in[1];
    const float* w_q = (const float*)d_in[2];
    const float* w_k = (const float*)d_in[3];
    const float* w_v = (const float*)d_in[4];
    const float* w_o = (const float*)d_in[5];

    float* out   = (float*)d_out;
    float* out_k = out + (size_t)S_LEN * DMODEL;
    float* out_v = out_k + (size_t)NKV * S_LEN * HD;

    // ---- workspace arena ----
    char* ws = (char*)d_ws;
    size_t off = 0;
    auto alloc = [&](size_t bytes) { char* p = ws + off; off += (bytes + 255) & ~255ull; return p; };
    float* cost = (float*)alloc((size_t)S_LEN * 64 * 4);
    float* sint = (float*)alloc((size_t)S_LEN * 64 * 4);
    float* Q32  = (float*)alloc((size_t)S_LEN * QDIM * 4);       // later: AOH
    u16* XH  = (u16*)alloc((size_t)S_LEN * DMODEL * 2);          // later: KH
    u16* XL  = (u16*)alloc((size_t)S_LEN * DMODEL * 2);          // later: KL
    u16* WBH = (u16*)alloc((size_t)NB * DMODEL * 2);             // later: VT + QL
    u16* WBL = (u16*)alloc((size_t)NB * DMODEL * 2);             // later: QH
    u16* WOH = (u16*)alloc((size_t)DMODEL * QDIM * 2);
    u16* AOH = (u16*)Q32;
    u16* KH  = XH;
    u16* KL  = XL;
    u16* QH  = WBL;
    u16* VT  = WBH;
    u16* QL  = WBH + (size_t)NKV * HD * S_LEN;

    // 1. all input prep (splits + packed WB + rope tables) in one launch
    prep_all<<<PREP_TOTAL / 256, 256, 0, stream>>>(
        x, w_q, w_k, w_v, w_o, pos, XH, XL, WBH, WBL, WOH, cost, sint);

    // 2. fused Q/K/V projections (8-phase template, 256 blocks)
    gemm_qkv5<<<256, 512, 0, stream>>>(XH, XL, WBH, WBL, Q32, out_k, out_v);

    // 3. V^T + fused rope/scale/split for q and k
    vt_transpose<<<dim3(64, 8), 256, 0, stream>>>(out_v, VT);
    rope_qk_split<<<(S_LEN * (NH + NKV) * 64) / 256, 256, 0, stream>>>(
        Q32, out_k, cost, sint, QH, QL, KH, KL);

    // 4. attention -> bf16 AO (3-slot ring, counted-vmcnt pipeline)
    attn_mfma9<<<512, 256, 0, stream>>>(QH, QL, KH, KL, VT, AOH);

    // 5. O projection (deep-pipelined)
    gemm_o3<<<256, 256, 0, stream>>>(AOH, WOH, out);
}

// Round 16
// 426.180 us; speedup vs baseline: 1.0343x; 1.0343x over previous
//
#include <hip/hip_runtime.h>
#include <math.h>

#define S_LEN 2048
#define DMODEL 2560
#define NH 32
#define NKV 8
#define HD 128
#define QDIM (NH*HD)     // 4096
#define KVDIM (NKV*HD)   // 1024
#define NB (QDIM + 2*KVDIM)   // 6144 packed B rows
#define ROPE_THETA 5000000.0
#define QK_SCALE 0.08838834764831843f

typedef __attribute__((ext_vector_type(8))) short s16x8;
typedef __attribute__((ext_vector_type(4))) float f32x4;
typedef __attribute__((ext_vector_type(16))) float f32x16;
typedef unsigned short u16;

#define MFMA16(a,b,c) __builtin_amdgcn_mfma_f32_16x16x32_bf16((a),(b),(c),0,0,0)
#define MFMA32(a,b,c) __builtin_amdgcn_mfma_f32_32x32x16_bf16((a),(b),(c),0,0,0)

__device__ __forceinline__ u16 f2bf(float x) {
    union { float f; unsigned u; } v; v.f = x;
    unsigned r = v.u + 0x7FFFu + ((v.u >> 16) & 1u);
    return (u16)(r >> 16);
}
__device__ __forceinline__ float bf2f(u16 h) {
    union { unsigned u; float f; } v; v.u = ((unsigned)h) << 16;
    return v.f;
}
__device__ __forceinline__ unsigned pk2(float a, float b) {
    return (unsigned)f2bf(a) | ((unsigned)f2bf(b) << 16);
}

// K arrays: [rows][16 units of 8 bf16], XOR all 4 unit bits.
__device__ __forceinline__ int lswK(int row, int kb) {
    return ((row * 16 + (kb ^ (row & 15))) << 3);
}

// async global->LDS, 16B per lane; LDS dest = wave-uniform base + lane*16.
__device__ __forceinline__ void gload16(const void* g, void* l) {
    __builtin_amdgcn_global_load_lds(
        (const __attribute__((address_space(1))) void*)g,
        (__attribute__((address_space(3))) void*)l, 16, 0, 0);
}

// ---------------------------------------------------------------------------
// prep_all: all input-side elementwise work in ONE launch.
// ---------------------------------------------------------------------------
#define N4_X   (S_LEN*DMODEL/4)
#define N4_WQ  (QDIM*DMODEL/4)
#define N4_WKV (KVDIM*DMODEL/4)
#define N4_WO  (DMODEL*QDIM/4)
#define N_TAB  (S_LEN*64)
#define PREP_TOTAL (N4_X + N4_WQ + N4_WKV + N4_WKV + N4_WO + N_TAB)

__device__ __forceinline__ void split4(const float* in, long i,
                                       u16* hi, u16* lo) {
    float4 v = ((const float4*)in)[i];
    float a[4] = {v.x, v.y, v.z, v.w};
    u16 hh[4], ll[4];
    #pragma unroll
    for (int j = 0; j < 4; ++j) {
        hh[j] = f2bf(a[j]);
        ll[j] = f2bf(a[j] - bf2f(hh[j]));
    }
    ((uint2*)hi)[i] = make_uint2((unsigned)hh[0] | ((unsigned)hh[1] << 16),
                                 (unsigned)hh[2] | ((unsigned)hh[3] << 16));
    ((uint2*)lo)[i] = make_uint2((unsigned)ll[0] | ((unsigned)ll[1] << 16),
                                 (unsigned)ll[2] | ((unsigned)ll[3] << 16));
}
__device__ __forceinline__ void cvt4(const float* in, long i, u16* out) {
    float4 v = ((const float4*)in)[i];
    u16 h0 = f2bf(v.x), h1 = f2bf(v.y), h2 = f2bf(v.z), h3 = f2bf(v.w);
    ((uint2*)out)[i] = make_uint2((unsigned)h0 | ((unsigned)h1 << 16),
                                  (unsigned)h2 | ((unsigned)h3 << 16));
}

__global__ __launch_bounds__(256)
void prep_all(const float* __restrict__ x, const float* __restrict__ w_q,
              const float* __restrict__ w_k, const float* __restrict__ w_v,
              const float* __restrict__ w_o, const int* __restrict__ pos,
              u16* __restrict__ XH, u16* __restrict__ XL,
              u16* __restrict__ WBH, u16* __restrict__ WBL,
              u16* __restrict__ WOH,
              float* __restrict__ cost, float* __restrict__ sint) {
    long i = (long)blockIdx.x * 256 + threadIdx.x;
    if (i < N4_X) { split4(x, i, XH, XL); return; }
    i -= N4_X;
    if (i < N4_WQ) { split4(w_q, i, WBH, WBL); return; }
    i -= N4_WQ;
    if (i < N4_WKV) {
        split4(w_k, i, WBH + (size_t)QDIM * DMODEL, WBL + (size_t)QDIM * DMODEL);
        return;
    }
    i -= N4_WKV;
    if (i < N4_WKV) {
        split4(w_v, i, WBH + (size_t)(QDIM + KVDIM) * DMODEL,
                       WBL + (size_t)(QDIM + KVDIM) * DMODEL);
        return;
    }
    i -= N4_WKV;
    if (i < N4_WO) { cvt4(w_o, i, WOH); return; }
    i -= N4_WO;
    if (i < N_TAB) {
        int s = (int)(i >> 6), j = (int)(i & 63);
        double inv = pow((double)ROPE_THETA, -(double)j / 64.0);
        double ang = (double)pos[s] * inv;
        cost[i] = (float)cos(ang);
        sint[i] = (float)sin(ang);
    }
}

// ---------------------------------------------------------------------------
// merged rope: q (scaled, ws) + k (in-place fp32 cache) -> bf16 hi/lo splits
// ---------------------------------------------------------------------------
__global__ __launch_bounds__(256)
void rope_qk_split(float* __restrict__ q32, float* __restrict__ k,
                   const float* __restrict__ cost, const float* __restrict__ sint,
                   u16* __restrict__ qhh, u16* __restrict__ qll,
                   u16* __restrict__ khh, u16* __restrict__ kll) {
    int idx = blockIdx.x * 256 + threadIdx.x;
    if (idx < S_LEN * NH * 64) {
        int j = idx & 63;
        int h = (idx >> 6) & 31;
        int s = idx >> 11;
        float c = cost[(s << 6) + j], sn = sint[(s << 6) + j];
        size_t base = (size_t)s * QDIM + (size_t)h * HD;
        float x1 = q32[base + j], x2 = q32[base + 64 + j];
        float y1 = (x1 * c - x2 * sn) * QK_SCALE;
        float y2 = (x2 * c + x1 * sn) * QK_SCALE;
        u16 h1 = f2bf(y1), h2 = f2bf(y2);
        qhh[base + j] = h1;      qll[base + j] = f2bf(y1 - bf2f(h1));
        qhh[base + 64 + j] = h2; qll[base + 64 + j] = f2bf(y2 - bf2f(h2));
    } else {
        idx -= S_LEN * NH * 64;
        int j = idx & 63;
        int s = (idx >> 6) & 2047;
        int h = idx >> 17;
        float c = cost[(s << 6) + j], sn = sint[(s << 6) + j];
        size_t base = ((size_t)h * S_LEN + s) * HD;
        float x1 = k[base + j], x2 = k[base + 64 + j];
        float y1 = x1 * c - x2 * sn;
        float y2 = x2 * c + x1 * sn;
        k[base + j] = y1; k[base + 64 + j] = y2;
        u16 h1 = f2bf(y1), h2 = f2bf(y2);
        khh[base + j] = h1;      kll[base + j] = f2bf(y1 - bf2f(h1));
        khh[base + 64 + j] = h2; kll[base + 64 + j] = f2bf(y2 - bf2f(h2));
    }
}

// ---------------------------------------------------------------------------
// V^T builder: v [8][2048][128] fp32 -> vt [8][128][2048] bf16 (coalesced).
// ---------------------------------------------------------------------------
__global__ __launch_bounds__(256)
void vt_transpose(const float* __restrict__ v, u16* __restrict__ vt) {
    __shared__ u16 t[64][80];
    const int kvh = blockIdx.y;
    const int st = blockIdx.x >> 1, dt = blockIdx.x & 1;
    const int tid = threadIdx.x;
    const int r = tid & 15, c4 = (tid >> 4) * 4;
    const float* vb = v + ((size_t)kvh * S_LEN + st * 64) * HD + dt * 64;
    #pragma unroll
    for (int p = 0; p < 4; ++p) {
        int row = p * 16 + r;
        float4 x = *(const float4*)&vb[(size_t)row * HD + c4];
        t[c4 + 0][row] = f2bf(x.x);
        t[c4 + 1][row] = f2bf(x.y);
        t[c4 + 2][row] = f2bf(x.z);
        t[c4 + 3][row] = f2bf(x.w);
    }
    __syncthreads();
    #pragma unroll
    for (int p = 0; p < 2; ++p) {
        int idx = p * 256 + tid;
        int dr = idx >> 3, sc = idx & 7;
        size_t o = ((size_t)kvh * HD + dt * 64 + dr) * S_LEN + st * 64 + sc * 8;
        *(int4*)&vt[o] = *(const int4*)&t[dr][sc * 8];
    }
}

// ---------------------------------------------------------------------------
// gemm_qkv6: combined-stage split-3 QKV projection.
// Per K=32 window: stage Ah,Al,Bh,Bl ONCE; compute ah.bh + ah.bl + al.bh
// (3x MFMA per staged byte vs the segmented sweep -> 80 windows not 240;
// per-window fixed overhead amortized 3x). BM=128, BN=192, 8 waves (2M x 4N,
// wave 64x48, acc 48 VGPR). 2-slot ring (80KB, 1 block/CU); gate =
// vmcnt(0)+barrier; stage(j+1) issued at window top (lead ~1 window
// ~1500cyc > HBM latency). Grid 512 = 16m x 32n; m-tile=bid&15 -> m%8 XCD.
// ---------------------------------------------------------------------------
__global__ __launch_bounds__(512, 2)
void gemm_qkv6(const u16* __restrict__ XH, const u16* __restrict__ XL,
               const u16* __restrict__ WBH, const u16* __restrict__ WBL,
               float* __restrict__ Q32, float* __restrict__ out_k,
               float* __restrict__ out_v) {
    __shared__ u16 SM[40960];   // 2 slots x (Ah 4096 | Al 4096 | Bh 6144 | Bl 6144)
    const int bid = blockIdx.x;
    const int m0 = (bid & 15) * 128;
    const int n0 = (bid >> 4) * 192;
    const int tid = threadIdx.x, lane = tid & 63, w = tid >> 6;
    const int q4 = lane >> 4, r15 = lane & 15;
    const int wm = (w >> 2) * 64, wn = (w & 3) * 48;

    f32x4 acc[4][3];
    #pragma unroll
    for (int i = 0; i < 4; ++i)
        #pragma unroll
        for (int jj = 0; jj < 3; ++jj) acc[i][jj] = (f32x4)(0.0f);

    // stage K-window j into slot j&1. A tiles: 8 chunks of 1KB (wave w ->
    // chunk w); B tiles: 12 chunks (wave w -> chunk w; waves 0-3 also 8+w).
    // Packed [row/2][8 units], unit pre-swizzled (inverse of lp8 read).
    auto stage = [&](int j) {
        const int s = j & 1;
        const int koff = j * 32;
        u16* S = &SM[s * 20480];
        {
            int uu = w * 64 + lane;
            int rl = uu >> 3, ulog = (uu & 7) ^ (rl & 7);
            int grow = m0 + rl * 2 + (ulog >> 2);
            size_t go = (size_t)grow * DMODEL + koff + (ulog & 3) * 8;
            gload16(XH + go, S + w * 512);
            gload16(XL + go, S + 4096 + w * 512);
        }
        {
            int uu = w * 64 + lane;
            int rl = uu >> 3, ulog = (uu & 7) ^ (rl & 7);
            int grow = n0 + rl * 2 + (ulog >> 2);
            size_t go = (size_t)grow * DMODEL + koff + (ulog & 3) * 8;
            gload16(WBH + go, S + 8192 + w * 512);
            gload16(WBL + go, S + 14336 + w * 512);
        }
        if (w < 4) {
            int c = 8 + w;
            int uu = c * 64 + lane;
            int rl = uu >> 3, ulog = (uu & 7) ^ (rl & 7);
            int grow = n0 + rl * 2 + (ulog >> 2);
            size_t go = (size_t)grow * DMODEL + koff + (ulog & 3) * 8;
            gload16(WBH + go, S + 8192 + c * 512);
            gload16(WBL + go, S + 14336 + c * 512);
        }
    };

    stage(0);

    const int NT = DMODEL / 32;   // 80 windows
    for (int j = 0; j < NT; ++j) {
        const int s = j & 1;
        __builtin_amdgcn_sched_barrier(0);
        asm volatile("s_waitcnt vmcnt(0)" ::: "memory");  // stage(j) landed
        __builtin_amdgcn_s_barrier();                     // all waves past j-1
        __builtin_amdgcn_sched_barrier(0);
        if (j + 1 < NT) stage(j + 1);   // slot (j+1)&1: readers done at barrier

        const u16* Ah = &SM[s * 20480];
        const u16* Al = Ah + 4096;
        const u16* Bh = Ah + 8192;
        const u16* Bl = Ah + 14336;
        auto rd = [&](const u16* T, int row) {
            int rl = row >> 1, ulog = (row & 1) * 4 + q4;
            return *(const s16x8*)&T[(rl * 8 + (ulog ^ (rl & 7))) * 8];
        };

        s16x8 bh0 = rd(Bh, wn + r15), bh1 = rd(Bh, wn + 16 + r15), bh2 = rd(Bh, wn + 32 + r15);
        s16x8 bl0 = rd(Bl, wn + r15), bl1 = rd(Bl, wn + 16 + r15), bl2 = rd(Bl, wn + 32 + r15);
        #pragma unroll
        for (int i = 0; i < 4; ++i) {
            int row = wm + i * 16 + r15;
            s16x8 ah = rd(Ah, row);
            s16x8 al = rd(Al, row);
            __builtin_amdgcn_s_setprio(1);
            acc[i][0] = MFMA16(ah, bh0, acc[i][0]);
            acc[i][1] = MFMA16(ah, bh1, acc[i][1]);
            acc[i][2] = MFMA16(ah, bh2, acc[i][2]);
            acc[i][0] = MFMA16(ah, bl0, acc[i][0]);
            acc[i][1] = MFMA16(ah, bl1, acc[i][1]);
            acc[i][2] = MFMA16(ah, bl2, acc[i][2]);
            acc[i][0] = MFMA16(al, bh0, acc[i][0]);
            acc[i][1] = MFMA16(al, bh1, acc[i][1]);
            acc[i][2] = MFMA16(al, bh2, acc[i][2]);
            __builtin_amdgcn_s_setprio(0);
        }
    }

    // epilogue: D layout col = lane&15, row = (lane>>4)*4 + r; region branch
    #pragma unroll
    for (int i = 0; i < 4; ++i) {
        #pragma unroll
        for (int jj = 0; jj < 3; ++jj) {
            int col = n0 + wn + jj * 16 + r15;
            #pragma unroll
            for (int r = 0; r < 4; ++r) {
                int row = m0 + wm + i * 16 + q4 * 4 + r;
                float v = acc[i][jj][r];
                if (col < QDIM) {
                    Q32[(size_t)row * QDIM + col] = v;
                } else if (col < QDIM + KVDIM) {
                    int cc = col - QDIM;
                    out_k[((size_t)(cc >> 7) * S_LEN + row) * HD + (cc & 127)] = v;
                } else {
                    int cc = col - QDIM - KVDIM;
                    out_v[((size_t)(cc >> 7) * S_LEN + row) * HD + (cc & 127)] = v;
                }
            }
        }
    }
}

// ---------------------------------------------------------------------------
// gemm_o3: deep-pipelined O projection (round-11/14 structure, unchanged).
// ---------------------------------------------------------------------------
__global__ __launch_bounds__(256, 2)
void gemm_o3(const u16* __restrict__ AOH, const u16* __restrict__ WOH,
             float* __restrict__ out) {
    __shared__ u16 SM[36864];     // A: 4 x 4096 | B: 4 x 5120 (u16)
    const int bid = blockIdx.x;
    const int m0 = (bid & 15) * 128;
    const int n0 = (bid >> 4) * 160;
    const int tid = threadIdx.x, lane = tid & 63, w = tid >> 6;
    const int q4 = lane >> 4, r15 = lane & 15;
    const int wm = (w >> 1) * 64, wn = (w & 1) * 80;

    f32x4 acc[4][5];
    #pragma unroll
    for (int i = 0; i < 4; ++i)
        #pragma unroll
        for (int jj = 0; jj < 5; ++jj) acc[i][jj] = (f32x4)(0.0f);

    auto stageA = [&](int j) {
        const int s = j & 3;
        const int koff = j * 32;
        #pragma unroll
        for (int p = 0; p < 2; ++p) {
            int c = p * 4 + w;
            int u = c * 64 + lane;
            int rl = u >> 3;
            int ulog = (u & 7) ^ (rl & 7);
            int grow = m0 + rl * 2 + (ulog >> 2);
            gload16(AOH + (size_t)grow * QDIM + koff + (ulog & 3) * 8,
                    &SM[s * 4096 + c * 512]);
        }
    };
    auto stageB = [&](int j) {
        const int s = j & 3;
        const int koff = j * 32;
        #pragma unroll
        for (int p = 0; p < 3; ++p) {
            int c = p * 4 + w;
            if (c < 10) {
                int u = c * 64 + lane;
                int rl = u >> 3;
                int ulog = (u & 7) ^ (rl & 7);
                int grow = n0 + rl * 2 + (ulog >> 2);
                gload16(WOH + (size_t)grow * QDIM + koff + (ulog & 3) * 8,
                        &SM[16384 + s * 5120 + c * 512]);
            }
        }
    };

    stageA(0); stageB(0); stageA(1); stageB(1);

    const int NT = QDIM / 32;     // 128
    for (int j = 0; j < NT; ++j) {
        const int s = j & 3;
        __builtin_amdgcn_sched_barrier(0);
        if (j + 1 < NT) {
            if (w < 2) { asm volatile("s_waitcnt vmcnt(5)" ::: "memory"); }
            else       { asm volatile("s_waitcnt vmcnt(4)" ::: "memory"); }
        } else {
            asm volatile("s_waitcnt vmcnt(0)" ::: "memory");
        }
        __builtin_amdgcn_s_barrier();
        __builtin_amdgcn_sched_barrier(0);

        if (j + 2 < NT) stageA(j + 2);

        u16* As = &SM[s * 4096];
        u16* Bs = &SM[16384 + s * 5120];
        auto Ard = [&](int i) {
            int row = wm + i * 16 + r15;
            int rl = row >> 1, ulog = (row & 1) * 4 + q4;
            return *(const s16x8*)&As[(rl * 8 + (ulog ^ (rl & 7))) * 8];
        };
        auto Brd = [&](int jj) {
            int row = wn + jj * 16 + r15;
            int rl = row >> 1, ulog = (row & 1) * 4 + q4;
            return *(const s16x8*)&Bs[(rl * 8 + (ulog ^ (rl & 7))) * 8];
        };

        s16x8 bf0 = Brd(0), bf1 = Brd(1), bf2 = Brd(2), bf3 = Brd(3), bf4 = Brd(4);
        s16x8 a0 = Ard(0);
        s16x8 a1 = Ard(1);
        __builtin_amdgcn_s_setprio(1);
        acc[0][0] = MFMA16(a0, bf0, acc[0][0]);
        acc[0][1] = MFMA16(a0, bf1, acc[0][1]);
        acc[0][2] = MFMA16(a0, bf2, acc[0][2]);
        acc[0][3] = MFMA16(a0, bf3, acc[0][3]);
        acc[0][4] = MFMA16(a0, bf4, acc[0][4]);
        __builtin_amdgcn_s_setprio(0);
        if (j + 2 < NT) stageB(j + 2);
        __builtin_amdgcn_s_setprio(1);
        s16x8 a2 = Ard(2);
        acc[1][0] = MFMA16(a1, bf0, acc[1][0]);
        acc[1][1] = MFMA16(a1, bf1, acc[1][1]);
        acc[1][2] = MFMA16(a1, bf2, acc[1][2]);
        acc[1][3] = MFMA16(a1, bf3, acc[1][3]);
        acc[1][4] = MFMA16(a1, bf4, acc[1][4]);
        s16x8 a3 = Ard(3);
        acc[2][0] = MFMA16(a2, bf0, acc[2][0]);
        acc[2][1] = MFMA16(a2, bf1, acc[2][1]);
        acc[2][2] = MFMA16(a2, bf2, acc[2][2]);
        acc[2][3] = MFMA16(a2, bf3, acc[2][3]);
        acc[2][4] = MFMA16(a2, bf4, acc[2][4]);
        acc[3][0] = MFMA16(a3, bf0, acc[3][0]);
        acc[3][1] = MFMA16(a3, bf1, acc[3][1]);
        acc[3][2] = MFMA16(a3, bf2, acc[3][2]);
        acc[3][3] = MFMA16(a3, bf3, acc[3][3]);
        acc[3][4] = MFMA16(a3, bf4, acc[3][4]);
        __builtin_amdgcn_s_setprio(0);
    }

    #pragma unroll
    for (int i = 0; i < 4; ++i) {
        #pragma unroll
        for (int jj = 0; jj < 5; ++jj) {
            int col = n0 + wn + jj * 16 + r15;
            #pragma unroll
            for (int r = 0; r < 4; ++r) {
                int row = m0 + wm + i * 16 + q4 * 4 + r;
                out[(size_t)row * DMODEL + col] = acc[i][jj][r];
            }
        }
    }
}

// ---------------------------------------------------------------------------
// MFMA flash attention v9 (round-11, unchanged): swapped 32x32 QK^T,
// per-lane softmax, KVBLK=32, 3-slot ring, counted-vmcnt gates.
// ---------------------------------------------------------------------------
__global__ __launch_bounds__(256, 2)
void attn_mfma9(const u16* __restrict__ qh, const u16* __restrict__ ql,
                const u16* __restrict__ kh, const u16* __restrict__ kl,
                const u16* __restrict__ vt, u16* __restrict__ aoh) {
    const int bid = blockIdx.x;
    const int kvh = bid & 7;
    const int s6 = bid >> 3;
    const int qst = (s6 < 32) ? s6 : 95 - s6;
    const int KT = qst + 1;

    const int tid = threadIdx.x, lane = tid & 63, w = tid >> 6;
    const int head = kvh * 4 + w;
    const int col = lane & 31;
    const int hi = lane >> 5;

    __shared__ u16 SMEM[36864];

    s16x8 qfh[8], qfl[8];
    {
        size_t qrow = (size_t)qst * 32 + col;
        const u16* qb  = qh + qrow * QDIM + (size_t)head * HD + hi * 8;
        const u16* qb2 = ql + qrow * QDIM + (size_t)head * HD + hi * 8;
        #pragma unroll
        for (int db = 0; db < 8; ++db) {
            qfh[db] = *(const s16x8*)(qb + db * 16);
            qfl[db] = *(const s16x8*)(qb2 + db * 16);
        }
    }

    f32x16 acco[4];
    #pragma unroll
    for (int dt = 0; dt < 4; ++dt) acco[dt] = (f32x16)(0.0f);
    float m = -1e30f, l = 0.f;

    const u16* kbase = kh + (size_t)kvh * S_LEN * HD;
    const u16* lbase = kl + (size_t)kvh * S_LEN * HD;
    const u16* vbase = vt + (size_t)kvh * HD * S_LEN;

    auto stage = [&](int kt, int slot) {
        u16* S = SMEM + slot * 12288;
        #pragma unroll
        for (int i = 0; i < 6; ++i) {
            int c = w + 4 * i;
            if (c < 16) {
                int cc = c & 7;
                int u = cc * 64 + lane;
                int krow = u >> 4;
                int kb = (u & 15) ^ (krow & 15);
                size_t g = (size_t)(kt * 32 + krow) * HD + kb * 8;
                if (c < 8) gload16(kbase + g, S + cc * 512);
                else       gload16(lbase + g, S + 4096 + cc * 512);
            } else {
                int cc = c - 16;
                int u = cc * 64 + lane;
                int R = u >> 3, s3 = u & 7;
                int g3 = s3 ^ (R & 7);
                int d = R * 2 + (g3 >> 2);
                int kb = g3 & 3;
                gload16(vbase + (size_t)d * S_LEN + kt * 32 + kb * 8,
                        S + 8192 + cc * 512);
            }
        }
    };

    stage(0, 0);
    if (KT > 1) stage(1, 1);

    for (int kt = 0; kt < KT; ++kt) {
        const int slot = kt % 3;
        __builtin_amdgcn_sched_barrier(0);
        if (kt + 1 < KT) { asm volatile("s_waitcnt vmcnt(6)" ::: "memory"); }
        else             { asm volatile("s_waitcnt vmcnt(0)" ::: "memory"); }
        __builtin_amdgcn_s_barrier();
        __builtin_amdgcn_sched_barrier(0);
        if (kt + 2 < KT) stage(kt + 2, (kt + 2) % 3);

        u16* Khs = SMEM + slot * 12288;
        u16* Kls = Khs + 4096;
        u16* Vts = Khs + 8192;

        f32x16 sfA = (f32x16)(0.0f), sfB = (f32x16)(0.0f);
        __builtin_amdgcn_s_setprio(1);
        #pragma unroll
        for (int d = 0; d < 4; ++d) {
            int u = d * 2 + hi;
            s16x8 a0h = *(const s16x8*)&Khs[lswK(col, u)];
            s16x8 a0l = *(const s16x8*)&Kls[lswK(col, u)];
            sfA = MFMA32(a0h, qfh[d], sfA);
            sfA = MFMA32(a0l, qfh[d], sfA);
            sfA = MFMA32(a0h, qfl[d], sfA);
        }
        #pragma unroll
        for (int d = 4; d < 8; ++d) {
            int u = d * 2 + hi;
            s16x8 a0h = *(const s16x8*)&Khs[lswK(col, u)];
            s16x8 a0l = *(const s16x8*)&Kls[lswK(col, u)];
            sfB = MFMA32(a0h, qfh[d], sfB);
            sfB = MFMA32(a0l, qfh[d], sfB);
            sfB = MFMA32(a0h, qfl[d], sfB);
        }
        __builtin_amdgcn_s_setprio(0);
        f32x16 sf0 = sfA + sfB;

        if (kt == qst) {
            #pragma unroll
            for (int r = 0; r < 16; ++r) {
                int row = (r & 3) + 8 * (r >> 2) + 4 * hi;
                if (row > col) sf0[r] = -1e30f;
            }
        }

        float pm = sf0[0];
        #pragma unroll
        for (int r = 1; r < 16; ++r) pm = fmaxf(pm, sf0[r]);
        pm = fmaxf(pm, __shfl_xor(pm, 32));

        if (!__all(pm - m <= 8.0f)) {
            float mn = fmaxf(m, pm);
            float corr = __expf(m - mn);
            m = mn; l *= corr;
            float cv[16];
            #pragma unroll
            for (int r = 0; r < 16; ++r)
                cv[r] = __shfl(corr, (r & 3) + 8 * (r >> 2) + 4 * hi);
            #pragma unroll
            for (int dt = 0; dt < 4; ++dt)
                #pragma unroll
                for (int r = 0; r < 16; ++r) acco[dt][r] *= cv[r];
        }

        float p0[16], sum = 0.f;
        #pragma unroll
        for (int r = 0; r < 16; ++r) { p0[r] = __expf(sf0[r] - m); sum += p0[r]; }
        sum += __shfl_xor(sum, 32);
        l += sum;

        unsigned w0[8], x0[8];
        #pragma unroll
        for (int i = 0; i < 8; ++i) w0[i] = pk2(p0[2 * i], p0[2 * i + 1]);
        #pragma unroll
        for (int i = 0; i < 8; ++i) x0[i] = __shfl_xor(w0[i], 32);
        union { unsigned u[4]; s16x8 v; } fa;
        s16x8 pa00, pa01;
        fa.u[0] = hi ? x0[2] : w0[0]; fa.u[1] = hi ? x0[3] : w0[1];
        fa.u[2] = hi ? w0[2] : x0[0]; fa.u[3] = hi ? w0[3] : x0[1];
        pa00 = fa.v;
        fa.u[0] = hi ? x0[6] : w0[4]; fa.u[1] = hi ? x0[7] : w0[5];
        fa.u[2] = hi ? w0[6] : x0[4]; fa.u[3] = hi ? w0[7] : x0[5];
        pa01 = fa.v;

        __builtin_amdgcn_s_setprio(1);
        #pragma unroll
        for (int dt = 0; dt < 4; ++dt) {
            int d = dt * 32 + col;
            int R = d >> 1, r7 = R & 7, par = (d & 1) * 4;
            s16x8 vb00 = *(const s16x8*)&Vts[((R << 3) + ((par | hi) ^ r7)) << 3];
            s16x8 vb01 = *(const s16x8*)&Vts[((R << 3) + ((par | (2 + hi)) ^ r7)) << 3];
            acco[dt] = MFMA32(pa00, vb00, acco[dt]);
            acco[dt] = MFMA32(pa01, vb01, acco[dt]);
        }
        __builtin_amdgcn_s_setprio(0);
    }

    __syncthreads();
    float linv = 1.0f / l;
    float lv[16];
    #pragma unroll
    for (int r = 0; r < 16; ++r)
        lv[r] = __shfl(linv, (r & 3) + 8 * (r >> 2) + 4 * hi);

    u16* ob = SMEM;
    #pragma unroll
    for (int dt = 0; dt < 4; ++dt)
        #pragma unroll
        for (int r = 0; r < 16; ++r) {
            int row = (r & 3) + 8 * (r >> 2) + 4 * hi;
            ob[(w * 32 + row) * 128 + dt * 32 + col] = f2bf(acco[dt][r] * lv[r]);
        }
    __syncthreads();
    #pragma unroll
    for (int p = 0; p < 8; ++p) {
        int i = p * 256 + tid;
        int hq = i >> 4, c8 = (i & 15) * 8;
        int hh = hq >> 5, qq = hq & 31;
        size_t grow = (size_t)qst * 32 + qq;
        *(int4*)&aoh[grow * QDIM + (size_t)(kvh * 4 + hh) * HD + c8] =
            *(const int4*)&ob[hq * 128 + c8];
    }
}

// ---------------------------------------------------------------------------
extern "C" void kernel_launch(void* const* d_in, const int* in_sizes, int n_in,
                              void* d_out, int out_size, void* d_ws, size_t ws_size,
                              hipStream_t stream) {
    const float* x   = (const float*)d_in[0];
    const int*   pos = (const int*)d_in[1];
    const float* w_q = (const float*)d_in[2];
    const float* w_k = (const float*)d_in[3];
    const float* w_v = (const float*)d_in[4];
    const float* w_o = (const float*)d_in[5];

    float* out   = (float*)d_out;
    float* out_k = out + (size_t)S_LEN * DMODEL;
    float* out_v = out_k + (size_t)NKV * S_LEN * HD;

    // ---- workspace arena ----
    char* ws = (char*)d_ws;
    size_t off = 0;
    auto alloc = [&](size_t bytes) { char* p = ws + off; off += (bytes + 255) & ~255ull; return p; };
    float* cost = (float*)alloc((size_t)S_LEN * 64 * 4);
    float* sint = (float*)alloc((size_t)S_LEN * 64 * 4);
    float* Q32  = (float*)alloc((size_t)S_LEN * QDIM * 4);       // later: AOH
    u16* XH  = (u16*)alloc((size_t)S_LEN * DMODEL * 2);          // later: KH
    u16* XL  = (u16*)alloc((size_t)S_LEN * DMODEL * 2);          // later: KL
    u16* WBH = (u16*)alloc((size_t)NB * DMODEL * 2);             // later: VT + QL
    u16* WBL = (u16*)alloc((size_t)NB * DMODEL * 2);             // later: QH
    u16* WOH = (u16*)alloc((size_t)DMODEL * QDIM * 2);
    u16* AOH = (u16*)Q32;
    u16* KH  = XH;
    u16* KL  = XL;
    u16* QH  = WBL;
    u16* VT  = WBH;
    u16* QL  = WBH + (size_t)NKV * HD * S_LEN;

    // 1. all input prep (splits + packed WB + rope tables) in one launch
    prep_all<<<PREP_TOTAL / 256, 256, 0, stream>>>(
        x, w_q, w_k, w_v, w_o, pos, XH, XL, WBH, WBL, WOH, cost, sint);

    // 2. fused Q/K/V projections (combined-stage split-3, 512 blocks)
    gemm_qkv6<<<512, 512, 0, stream>>>(XH, XL, WBH, WBL, Q32, out_k, out_v);

    // 3. V^T + fused rope/scale/split for q and k
    vt_transpose<<<dim3(64, 8), 256, 0, stream>>>(out_v, VT);
    rope_qk_split<<<(S_LEN * (NH + NKV) * 64) / 256, 256, 0, stream>>>(
        Q32, out_k, cost, sint, QH, QL, KH, KL);

    // 4. attention -> bf16 AO (3-slot ring, counted-vmcnt pipeline)
    attn_mfma9<<<512, 256, 0, stream>>>(QH, QL, KH, KL, VT, AOH);

    // 5. O projection (deep-pipelined)
    gemm_o3<<<256, 256, 0, stream>>>(AOH, WOH, out);
}